// Round 10
// baseline (339.786 us; speedup 1.0000x reference)
//
#include <hip/hip_runtime.h>

constexpr int NN = 100000;
constexpr int NE = 1600000;
constexpr int NBUK = 196;            // 512-node buckets: 196*512 = 100352 >= NN
constexpr int ECAP = 10240;          // bucket capacity (E[cnt]=8192, sigma~90)
constexpr int CHUNK = 6250;          // edges per k_part1 block (256 blocks exact)
constexpr int NPT = 13;              // ceil(6250/512)

typedef __attribute__((ext_vector_type(8))) short bf16x8;
typedef __attribute__((ext_vector_type(4))) float f32x4;

__device__ inline ushort f2b(float f){
  uint u = __float_as_uint(f);
  uint r = (u + 0x7FFFu + ((u >> 16) & 1u)) >> 16;
  return (ushort)r;
}
__device__ inline float b2f(ushort u){
  uint v = ((uint)u) << 16;
  return __uint_as_float(v);
}

template<int CTRL>
__device__ inline float dpp_xadd(float v){
  int j = __builtin_amdgcn_update_dpp(0, __float_as_int(v), CTRL, 0xF, 0xF, true);
  return v + __int_as_float(j);
}
__device__ inline float red16(float v){
  v = dpp_xadd<0xB1>(v);
  v = dpp_xadd<0x4E>(v);
  v = dpp_xadd<0x141>(v);
  v = dpp_xadd<0x140>(v);
  return v;
}

// ---------------- CSR build, phase 1: block-local binning ----------------
__global__ __launch_bounds__(512) void k_part1(const int* __restrict__ srcA,
                                               const int* __restrict__ dstA,
                                               int* __restrict__ bukcur,
                                               int* __restrict__ ebuf){
  __shared__ int stage[CHUNK];
  __shared__ unsigned char bstage[CHUNK];
  __shared__ int hist[256];
  __shared__ int lofs[256];
  __shared__ int lcur[NBUK];
  __shared__ int basebuf[NBUK];
  int t = threadIdx.x;
  int cbase = blockIdx.x * CHUNK;

  if (t < 256) hist[t] = 0;
  if (t < NBUK) lcur[t] = 0;
  __syncthreads();

  int pk[NPT], bb[NPT];
  #pragma unroll
  for (int j = 0; j < NPT; ++j){
    int i = t + j*512;
    bb[j] = -1;
    if (i < CHUNK){
      int e = cbase + i;
      int d = dstA[e];
      bb[j] = d >> 9;
      pk[j] = (srcA[e] << 9) | (d & 511);
      atomicAdd(&hist[bb[j]], 1);
    }
  }
  __syncthreads();

  int v = (t < 256) ? hist[t] : 0;
  if (t < 256) lofs[t] = v;
  __syncthreads();
  #pragma unroll
  for (int off = 1; off < 256; off <<= 1){
    int tv = (t < 256 && t >= off) ? lofs[t-off] : 0;
    __syncthreads();
    if (t < 256) lofs[t] += tv;
    __syncthreads();
  }
  if (t < 256) lofs[t] -= v;
  if (t < NBUK) basebuf[t] = atomicAdd(&bukcur[t], v);
  __syncthreads();

  #pragma unroll
  for (int j = 0; j < NPT; ++j){
    if (bb[j] >= 0){
      int p = atomicAdd(&lcur[bb[j]], 1);
      int slot = lofs[bb[j]] + p;
      stage[slot] = pk[j];
      bstage[slot] = (unsigned char)bb[j];
    }
  }
  __syncthreads();

  for (int i = t; i < CHUNK; i += 512){
    int b = bstage[i];
    int j = i - lofs[b];
    int pos = basebuf[b] + j;
    if (pos < ECAP) ebuf[b*ECAP + pos] = stage[i];
  }
}

__global__ void k_bscan(const int* __restrict__ bukcur, int* __restrict__ bukptr){
  __shared__ int s[256];
  int t = threadIdx.x;
  int v = (t < NBUK) ? bukcur[t] : 0;
  s[t] = v; __syncthreads();
  #pragma unroll
  for (int off = 1; off < 256; off <<= 1){
    int tv = (t >= off) ? s[t-off] : 0;
    __syncthreads();
    s[t] += tv;
    __syncthreads();
  }
  if (t < NBUK) bukptr[t] = s[t] - v;
  if (t == NBUK-1) bukptr[NBUK] = s[t];
}

__global__ __launch_bounds__(512) void k_bfinal(const int* __restrict__ ebuf,
                                                const int* __restrict__ bukcur,
                                                const int* __restrict__ bukptr,
                                                int* __restrict__ rowptr,
                                                int* __restrict__ csr){
  __shared__ int lcnt[512];
  __shared__ int lscan[512];
  __shared__ int lcur[512];
  int b = blockIdx.x, t = threadIdx.x;
  int cnt = bukcur[b]; if (cnt > ECAP) cnt = ECAP;
  int base = b*ECAP, gbase = bukptr[b];

  lcnt[t] = 0; lcur[t] = 0;
  __syncthreads();
  for (int i = t; i < cnt; i += 512) atomicAdd(&lcnt[ebuf[base+i] & 511], 1);
  __syncthreads();
  int v = lcnt[t];
  lscan[t] = v; __syncthreads();
  #pragma unroll
  for (int off = 1; off < 512; off <<= 1){
    int tv = (t >= off) ? lscan[t-off] : 0;
    __syncthreads();
    lscan[t] += tv;
    __syncthreads();
  }
  int excl = lscan[t] - v;
  lcnt[t] = excl;
  int node = b*512 + t;
  if (node <= NN) rowptr[node] = gbase + excl;
  __syncthreads();
  for (int i = t; i < cnt; i += 512){
    int p = ebuf[base+i];
    int d = p & 511;
    int pos = atomicAdd(&lcur[d], 1);
    csr[gbase + lcnt[d] + pos] = p >> 9;
  }
}

// ---------------- x -> bf16 copy ----------------
__global__ void k_xb(const float* __restrict__ x, ushort* __restrict__ xb){
  int i = blockIdx.x*256 + threadIdx.x;
  float4 v = ((const float4*)x)[i];
  ushort4 o;
  o.x = f2b(v.x); o.y = f2b(v.y); o.z = f2b(v.z); o.w = f2b(v.w);
  ((ushort4*)xb)[i] = o;
}

// ---------------- effective-weight prep ----------------
__global__ void k_vchain(const float* __restrict__ Wp, float* __restrict__ V2,
                         float* __restrict__ V3){
  __shared__ float sA[4096], sB[4096], sC[4096];
  int t = threadIdx.x;
  for (int i = t; i < 4096; i += 256){ sA[i] = Wp[i]; sB[i] = Wp[4096+i]; }
  __syncthreads();
  for (int i = t; i < 4096; i += 256){
    int r = i >> 6, c = i & 63; float s = 0.f;
    #pragma unroll 8
    for (int j = 0; j < 64; ++j) s += sA[r*64+j]*sB[j*64+c];
    sC[i] = s; V2[i] = s;
  }
  __syncthreads();
  for (int i = t; i < 4096; i += 256) sB[i] = Wp[8192+i];
  __syncthreads();
  for (int i = t; i < 4096; i += 256){
    int r = i >> 6, c = i & 63; float s = 0.f;
    #pragma unroll 8
    for (int j = 0; j < 64; ++j) s += sC[r*64+j]*sB[j*64+c];
    V3[i] = s;
  }
}

__global__ void k_ueff(const float* __restrict__ W1, const float* __restrict__ Wp,
                       const float* __restrict__ V2, const float* __restrict__ V3,
                       ushort* __restrict__ W1t){
  __shared__ float col[256];
  int c = blockIdx.x, r = threadIdx.x;
  col[r] = W1[(size_t)r*512 + c];
  __syncthreads();
  int p = r >> 6, i = r & 63;
  float s;
  if (p == 0) s = col[r];
  else {
    const float* V = (p == 1) ? Wp : (p == 2) ? V2 : V3;
    s = 0.f;
    #pragma unroll 8
    for (int j = 0; j < 64; ++j) s += V[i*64+j]*col[p*64+j];
  }
  W1t[c*256 + r] = f2b(s);
}

__global__ void k_w2t(const float* __restrict__ W2, ushort* __restrict__ W2t){
  int col = blockIdx.x, k = threadIdx.x;
  W2t[col*512 + k] = f2b(W2[(size_t)k*64 + col]);
}

// ---------------- bf16 hop aggregation: 8 slots x 1 edge (stride 8), unroll 2 ----------------
__global__ void k_aggb(const ushort* __restrict__ hb, const int* __restrict__ rowptr,
                       const int* __restrict__ csr, ushort* __restrict__ yb){
  int lane = threadIdx.x & 63;
  int n = blockIdx.x*4 + (threadIdx.x >> 6);
  int f = lane & 7, s = lane >> 3;          // 8 feature-groups x 8 slots
  int beg = rowptr[n], end = rowptr[n+1];
  float a[8] = {};
  int e = beg + s;
  for (; e + 8 < end; e += 16){
    int i0 = csr[e], i1 = csr[e+8];
    bf16x8 v0 = *(const bf16x8*)(hb + (size_t)i0*64 + f*8);
    bf16x8 v1 = *(const bf16x8*)(hb + (size_t)i1*64 + f*8);
    #pragma unroll
    for (int j = 0; j < 8; ++j)
      a[j] += b2f((ushort)v0[j]) + b2f((ushort)v1[j]);
  }
  if (e < end){
    int i0 = csr[e];
    bf16x8 v = *(const bf16x8*)(hb + (size_t)i0*64 + f*8);
    #pragma unroll
    for (int j = 0; j < 8; ++j) a[j] += b2f((ushort)v[j]);
  }
  #pragma unroll
  for (int off = 8; off < 64; off <<= 1)
    #pragma unroll
    for (int j = 0; j < 8; ++j) a[j] += __shfl_xor(a[j], off);
  if (s == 0){
    float inv = 1.f / fmaxf((float)(end - beg), 1.f);
    bf16x8 o;
    #pragma unroll
    for (int j = 0; j < 8; ++j) o[j] = (short)f2b(a[j]*inv);
    *(bf16x8*)(yb + (size_t)n*64 + f*8) = o;
  }
}

// ---------------- fused MLP via bf16 MFMA: 32-row tiles, 3 blocks/CU ----------------
__global__ __launch_bounds__(512, 6) void k_mlp(
    const ushort* __restrict__ cat0,              // xb; y1/y2/y3 at +PSTR each
    const ushort* __restrict__ W1t, const float* __restrict__ b1,
    const float* __restrict__ gamma, const float* __restrict__ beta,
    const ushort* __restrict__ W2t, const float* __restrict__ b2,
    float* __restrict__ out){
  constexpr size_t PSTR = 6400000;                // ushorts between concat parts
  __shared__ char lbuf[32768];                    // A: 16KB (32x512B swz); h: 32KB (32x1024B swz)
  __shared__ float2 s_pair[8][32];
  __shared__ float2 s_stat2[32];

  int tid = threadIdx.x;
  int lane = tid & 63, wv = tid >> 6;
  int l15 = lane & 15, l4 = lane >> 4;

  int bid = blockIdx.x;
  {
    constexpr int NB = 3125, q = NB/8, r = NB%8;  // q=390, r=5
    int xcd = bid & 7, idx = bid >> 3;
    bid = (xcd < r ? xcd*(q+1) : r*(q+1) + (xcd-r)*q) + idx;
  }
  int nbase = bid * 32;                           // 3125*32 = 100000 exact

  // ---- stage A (32x256 bf16, XOR-swizzled) via global_load_lds ----
  #pragma unroll
  for (int i = 0; i < 2; ++i){
    int dest = (wv*2 + i)*1024 + lane*16;
    int row = dest >> 9;
    int kbyte = (dest & 511) ^ ((row & 7) << 4);
    const ushort* src = cat0 + (size_t)(kbyte >> 7)*PSTR
                             + (size_t)(nbase + row)*64 + ((kbyte & 127) >> 1);
    __builtin_amdgcn_global_load_lds(
        (const __attribute__((address_space(1))) void*)src,
        (__attribute__((address_space(3))) void*)(lbuf + (wv*2 + i)*1024),
        16, 0, 0);
  }
  __syncthreads();                                 // (0)

  #define LOADA(kb, d)                                                          \
    { _Pragma("unroll")                                                         \
      for (int rt = 0; rt < 2; ++rt){                                           \
        int row_ = rt*16 + l15;                                                 \
        d[rt] = *(const bf16x8*)(lbuf + row_*512 +                              \
                 (((kb)*64 + l4*16) ^ ((row_ & 7) << 4)));                      \
      } }
  #define LOADB(kb, d)                                                          \
    { _Pragma("unroll")                                                         \
      for (int ci = 0; ci < 4; ++ci)                                            \
        d[ci] = *(const bf16x8*)(W1t + (size_t)(wv*64 + ci*16 + l15)*256 +      \
                                 (kb)*32 + l4*8); }

  // ---- GEMM1: [32x256] @ [256x512]; wave owns cols [wv*64, wv*64+64) ----
  f32x4 acc[2][4] = {};
  {
    bf16x8 a[2], b[2][4];
    LOADB(0, b[0]);
    #pragma unroll
    for (int kb = 0; kb < 8; ++kb){
      int cur = kb & 1, nxt = cur ^ 1;
      if (kb < 7) LOADB(kb+1, b[nxt]);
      LOADA(kb, a);
      #pragma unroll
      for (int rt = 0; rt < 2; ++rt)
        #pragma unroll
        for (int ci = 0; ci < 4; ++ci)
          acc[rt][ci] = __builtin_amdgcn_mfma_f32_16x16x32_bf16(a[rt], b[cur][ci], acc[rt][ci], 0, 0, 0);
    }
  }

  // ---- bias + LN partial stats ----
  float bcol[4], gcol[4], ecol[4];
  #pragma unroll
  for (int ci = 0; ci < 4; ++ci){
    int col = wv*64 + ci*16 + l15;
    bcol[ci] = b1[col]; gcol[ci] = gamma[col]; ecol[ci] = beta[col];
  }
  #pragma unroll
  for (int rt = 0; rt < 2; ++rt)
    #pragma unroll
    for (int ci = 0; ci < 4; ++ci)
      #pragma unroll
      for (int r = 0; r < 4; ++r)
        acc[rt][ci][r] += bcol[ci];

  #pragma unroll
  for (int rt = 0; rt < 2; ++rt){
    #pragma unroll
    for (int r = 0; r < 4; ++r){
      float s = 0.f, q = 0.f;
      #pragma unroll
      for (int ci = 0; ci < 4; ++ci){
        float v = acc[rt][ci][r];
        s += v; q += v*v;
      }
      s = red16(s);
      q = red16(q);
      if (l15 == 0) s_pair[wv][rt*16 + l4*4 + r] = make_float2(s, q);
    }
  }
  __syncthreads();                                 // (1) A reads done

  if (tid < 32){
    float s = 0.f, q = 0.f;
    #pragma unroll
    for (int w = 0; w < 8; ++w){ float2 p = s_pair[w][tid]; s += p.x; q += p.y; }
    float mu = s * (1.f/512.f);
    float var = q * (1.f/512.f) - mu*mu;
    s_stat2[tid] = make_float2(mu, rsqrtf(var + 1e-5f));
  }
  __syncthreads();                                 // (2)

  // ---- LN + ReLU -> h tile (32 rows x 1024 B, swizzled) ----
  #pragma unroll
  for (int rt = 0; rt < 2; ++rt){
    #pragma unroll
    for (int r = 0; r < 4; ++r){
      int row = rt*16 + l4*4 + r;
      float2 st = s_stat2[row];
      #pragma unroll
      for (int ci = 0; ci < 4; ++ci){
        float hv = fmaxf((acc[rt][ci][r] - st.x)*st.y*gcol[ci] + ecol[ci], 0.f);
        int col = wv*64 + ci*16 + l15;
        *((ushort*)(lbuf + row*1024 + ((col*2) ^ ((row & 7) << 4)))) = f2b(hv);
      }
    }
  }
  __syncthreads();                                 // (3)

  // ---- GEMM2: h[32x512] @ W2[512x64]; wave -> out-tile (rt2 = wv>>2, ct = wv&3) ----
  int ct = wv & 3;
  int rt2 = wv >> 2;
  f32x4 acc2 = {};
  const ushort* w2base = W2t + (size_t)(ct*16 + l15)*512 + l4*8;
  {
    int row_ = rt2*16 + l15;
    bf16x8 hb2[2], w2f[2];
    w2f[0] = *(const bf16x8*)(w2base);
    hb2[0] = *(const bf16x8*)(lbuf + row_*1024 + ((l4*16) ^ ((row_ & 7) << 4)));
    #pragma unroll
    for (int kb = 0; kb < 16; ++kb){
      int cur = kb & 1, nxt = cur ^ 1;
      if (kb < 15){
        w2f[nxt] = *(const bf16x8*)(w2base + (kb+1)*32);
        hb2[nxt] = *(const bf16x8*)(lbuf + row_*1024 +
                     (((kb+1)*64 + l4*16) ^ ((row_ & 7) << 4)));
      }
      acc2 = __builtin_amdgcn_mfma_f32_16x16x32_bf16(hb2[cur], w2f[cur], acc2, 0, 0, 0);
    }
  }

  float b2v = b2[ct*16 + l15];
  #pragma unroll
  for (int r = 0; r < 4; ++r){
    int row = rt2*16 + l4*4 + r;
    out[(size_t)(nbase + row)*64 + ct*16 + l15] = acc2[r] + b2v;
  }
  #undef LOADA
  #undef LOADB
}

extern "C" void kernel_launch(void* const* d_in, const int* in_sizes, int n_in,
                              void* d_out, int out_size, void* d_ws, size_t ws_size,
                              hipStream_t stream){
  const float* x     = (const float*)d_in[0];
  const int*   eidx  = (const int*)d_in[1];
  const float* wprop = (const float*)d_in[2];
  const float* W1    = (const float*)d_in[3];
  const float* b1    = (const float*)d_in[4];
  const float* gamma = (const float*)d_in[5];
  const float* beta  = (const float*)d_in[6];
  const float* W2    = (const float*)d_in[7];
  const float* b2    = (const float*)d_in[8];
  float* out = (float*)d_out;
  const int* srcA = eidx;
  const int* dstA = eidx + NE;

  char* ws = (char*)d_ws;
  int*    rowptr = (int*)(ws);                  // 400,128 B -> pad 400,384
  ushort* W1t    = (ushort*)(ws +   400384);    // 256 KB -> 662,528
  ushort* W2t    = (ushort*)(ws +   662528);    // 64 KB  -> 728,064
  float*  V2     = (float*)(ws +    728064);    // 16 KB  -> 744,448
  float*  V3     = (float*)(ws +    744448);    // 16 KB  -> 760,832
  int*    bukcur = (int*)(ws +      760832);    // pad -> 761,856
  int*    bukptr = (int*)(ws +      761856);    // pad -> 762,880
  int*    csr    = (int*)(ws +      762880);    // 6.4 MB -> 7,162,880
  int*    ebuf   = (int*)(ws +     7162880);    // 8,028,160 B -> 15,191,040
  ushort* xb     = (ushort*)(ws + 15191040);    // 12.8 MB -> 27,991,040
  ushort* y1     = (ushort*)(ws + 27991040);    // 12.8 MB -> 40,791,040
  ushort* y2     = (ushort*)(ws + 40791040);    // 12.8 MB -> 53,591,040
  ushort* y3     = (ushort*)(ws + 53591040);    // 12.8 MB -> 66,391,040

  // ---- CSR build (hierarchical bucketed counting sort) ----
  hipMemsetAsync(bukcur, 0, NBUK*sizeof(int), stream);
  k_part1<<<256, 512, 0, stream>>>(srcA, dstA, bukcur, ebuf);
  k_bscan<<<1, 256, 0, stream>>>(bukcur, bukptr);
  k_bfinal<<<NBUK, 512, 0, stream>>>(ebuf, bukcur, bukptr, rowptr, csr);

  // ---- weight/input prep ----
  k_xb<<<6250, 256, 0, stream>>>(x, xb);
  k_vchain<<<1, 256, 0, stream>>>(wprop, V2, V3);
  k_ueff<<<512, 256, 0, stream>>>(W1, wprop, V2, V3, W1t);
  k_w2t<<<64, 512, 0, stream>>>(W2, W2t);

  // ---- 3 hops ----
  k_aggb<<<25000, 256, 0, stream>>>(xb, rowptr, csr, y1);
  k_aggb<<<25000, 256, 0, stream>>>(y1, rowptr, csr, y2);
  k_aggb<<<25000, 256, 0, stream>>>(y2, rowptr, csr, y3);

  // ---- fused MLP (32-row tiles) ----
  k_mlp<<<3125, 512, 0, stream>>>(xb, W1t, b1, gamma, beta, W2t, b2, out);
}

// Round 11
// 336.928 us; speedup vs baseline: 1.0085x; 1.0085x over previous
//
#include <hip/hip_runtime.h>

constexpr int NN = 100000;
constexpr int NE = 1600000;
constexpr int NBUK = 196;            // 512-node buckets: 196*512 = 100352 >= NN
constexpr int ECAP = 10240;          // bucket capacity (E[cnt]=8192, sigma~90)
constexpr int CHUNK = 6250;          // edges per k_part1 block (256 blocks exact)
constexpr int NPT = 13;              // ceil(6250/512)

typedef __attribute__((ext_vector_type(8))) short bf16x8;
typedef __attribute__((ext_vector_type(4))) float f32x4;

__device__ inline ushort f2b(float f){
  uint u = __float_as_uint(f);
  uint r = (u + 0x7FFFu + ((u >> 16) & 1u)) >> 16;
  return (ushort)r;
}
__device__ inline float b2f(ushort u){
  uint v = ((uint)u) << 16;
  return __uint_as_float(v);
}

// ---------------- CSR build, phase 1: block-local binning ----------------
__global__ __launch_bounds__(512) void k_part1(const int* __restrict__ srcA,
                                               const int* __restrict__ dstA,
                                               int* __restrict__ bukcur,
                                               int* __restrict__ ebuf){
  __shared__ int stage[CHUNK];
  __shared__ unsigned char bstage[CHUNK];
  __shared__ int hist[256];
  __shared__ int lofs[256];
  __shared__ int lcur[NBUK];
  __shared__ int basebuf[NBUK];
  int t = threadIdx.x;
  int cbase = blockIdx.x * CHUNK;

  if (t < 256) hist[t] = 0;
  if (t < NBUK) lcur[t] = 0;
  __syncthreads();

  int pk[NPT], bb[NPT];
  #pragma unroll
  for (int j = 0; j < NPT; ++j){
    int i = t + j*512;
    bb[j] = -1;
    if (i < CHUNK){
      int e = cbase + i;
      int d = dstA[e];
      bb[j] = d >> 9;
      pk[j] = (srcA[e] << 9) | (d & 511);
      atomicAdd(&hist[bb[j]], 1);
    }
  }
  __syncthreads();

  int v = (t < 256) ? hist[t] : 0;
  if (t < 256) lofs[t] = v;
  __syncthreads();
  #pragma unroll
  for (int off = 1; off < 256; off <<= 1){
    int tv = (t < 256 && t >= off) ? lofs[t-off] : 0;
    __syncthreads();
    if (t < 256) lofs[t] += tv;
    __syncthreads();
  }
  if (t < 256) lofs[t] -= v;
  if (t < NBUK) basebuf[t] = atomicAdd(&bukcur[t], v);
  __syncthreads();

  #pragma unroll
  for (int j = 0; j < NPT; ++j){
    if (bb[j] >= 0){
      int p = atomicAdd(&lcur[bb[j]], 1);
      int slot = lofs[bb[j]] + p;
      stage[slot] = pk[j];
      bstage[slot] = (unsigned char)bb[j];
    }
  }
  __syncthreads();

  for (int i = t; i < CHUNK; i += 512){
    int b = bstage[i];
    int j = i - lofs[b];
    int pos = basebuf[b] + j;
    if (pos < ECAP) ebuf[b*ECAP + pos] = stage[i];
  }
}

__global__ void k_bscan(const int* __restrict__ bukcur, int* __restrict__ bukptr){
  __shared__ int s[256];
  int t = threadIdx.x;
  int v = (t < NBUK) ? bukcur[t] : 0;
  s[t] = v; __syncthreads();
  #pragma unroll
  for (int off = 1; off < 256; off <<= 1){
    int tv = (t >= off) ? s[t-off] : 0;
    __syncthreads();
    s[t] += tv;
    __syncthreads();
  }
  if (t < NBUK) bukptr[t] = s[t] - v;
  if (t == NBUK-1) bukptr[NBUK] = s[t];
}

__global__ __launch_bounds__(512) void k_bfinal(const int* __restrict__ ebuf,
                                                const int* __restrict__ bukcur,
                                                const int* __restrict__ bukptr,
                                                int* __restrict__ rowptr,
                                                int* __restrict__ csr){
  __shared__ int lcnt[512];
  __shared__ int lscan[512];
  __shared__ int lcur[512];
  int b = blockIdx.x, t = threadIdx.x;
  int cnt = bukcur[b]; if (cnt > ECAP) cnt = ECAP;
  int base = b*ECAP, gbase = bukptr[b];

  lcnt[t] = 0; lcur[t] = 0;
  __syncthreads();
  for (int i = t; i < cnt; i += 512) atomicAdd(&lcnt[ebuf[base+i] & 511], 1);
  __syncthreads();
  int v = lcnt[t];
  lscan[t] = v; __syncthreads();
  #pragma unroll
  for (int off = 1; off < 512; off <<= 1){
    int tv = (t >= off) ? lscan[t-off] : 0;
    __syncthreads();
    lscan[t] += tv;
    __syncthreads();
  }
  int excl = lscan[t] - v;
  lcnt[t] = excl;
  int node = b*512 + t;
  if (node <= NN) rowptr[node] = gbase + excl;
  __syncthreads();
  for (int i = t; i < cnt; i += 512){
    int p = ebuf[base+i];
    int d = p & 511;
    int pos = atomicAdd(&lcur[d], 1);
    csr[gbase + lcnt[d] + pos] = p >> 9;
  }
}

// ---------------- x -> bf16 copy ----------------
__global__ void k_xb(const float* __restrict__ x, ushort* __restrict__ xb){
  int i = blockIdx.x*256 + threadIdx.x;
  float4 v = ((const float4*)x)[i];
  ushort4 o;
  o.x = f2b(v.x); o.y = f2b(v.y); o.z = f2b(v.z); o.w = f2b(v.w);
  ((ushort4*)xb)[i] = o;
}

// ---------------- effective-weight prep ----------------
__global__ void k_vchain(const float* __restrict__ Wp, float* __restrict__ V2,
                         float* __restrict__ V3){
  __shared__ float sA[4096], sB[4096], sC[4096];
  int t = threadIdx.x;
  for (int i = t; i < 4096; i += 256){ sA[i] = Wp[i]; sB[i] = Wp[4096+i]; }
  __syncthreads();
  for (int i = t; i < 4096; i += 256){
    int r = i >> 6, c = i & 63; float s = 0.f;
    #pragma unroll 8
    for (int j = 0; j < 64; ++j) s += sA[r*64+j]*sB[j*64+c];
    sC[i] = s; V2[i] = s;
  }
  __syncthreads();
  for (int i = t; i < 4096; i += 256) sB[i] = Wp[8192+i];
  __syncthreads();
  for (int i = t; i < 4096; i += 256){
    int r = i >> 6, c = i & 63; float s = 0.f;
    #pragma unroll 8
    for (int j = 0; j < 64; ++j) s += sC[r*64+j]*sB[j*64+c];
    V3[i] = s;
  }
}

__global__ void k_ueff(const float* __restrict__ W1, const float* __restrict__ Wp,
                       const float* __restrict__ V2, const float* __restrict__ V3,
                       ushort* __restrict__ W1t){
  __shared__ float col[256];
  int c = blockIdx.x, r = threadIdx.x;
  col[r] = W1[(size_t)r*512 + c];
  __syncthreads();
  int p = r >> 6, i = r & 63;
  float s;
  if (p == 0) s = col[r];
  else {
    const float* V = (p == 1) ? Wp : (p == 2) ? V2 : V3;
    s = 0.f;
    #pragma unroll 8
    for (int j = 0; j < 64; ++j) s += V[i*64+j]*col[p*64+j];
  }
  W1t[c*256 + r] = f2b(s);
}

__global__ void k_w2t(const float* __restrict__ W2, ushort* __restrict__ W2t){
  int col = blockIdx.x, k = threadIdx.x;
  W2t[col*512 + k] = f2b(W2[(size_t)k*64 + col]);
}

// ---------------- bf16 hop aggregation: 8 slots x 1 edge (stride 8), unroll 2 ----------------
__global__ void k_aggb(const ushort* __restrict__ hb, const int* __restrict__ rowptr,
                       const int* __restrict__ csr, ushort* __restrict__ yb){
  int lane = threadIdx.x & 63;
  int n = blockIdx.x*4 + (threadIdx.x >> 6);
  int f = lane & 7, s = lane >> 3;          // 8 feature-groups x 8 slots
  int beg = rowptr[n], end = rowptr[n+1];
  float a[8] = {};
  int e = beg + s;
  for (; e + 8 < end; e += 16){
    int i0 = csr[e], i1 = csr[e+8];
    bf16x8 v0 = *(const bf16x8*)(hb + (size_t)i0*64 + f*8);
    bf16x8 v1 = *(const bf16x8*)(hb + (size_t)i1*64 + f*8);
    #pragma unroll
    for (int j = 0; j < 8; ++j)
      a[j] += b2f((ushort)v0[j]) + b2f((ushort)v1[j]);
  }
  if (e < end){
    int i0 = csr[e];
    bf16x8 v = *(const bf16x8*)(hb + (size_t)i0*64 + f*8);
    #pragma unroll
    for (int j = 0; j < 8; ++j) a[j] += b2f((ushort)v[j]);
  }
  #pragma unroll
  for (int off = 8; off < 64; off <<= 1)
    #pragma unroll
    for (int j = 0; j < 8; ++j) a[j] += __shfl_xor(a[j], off);
  if (s == 0){
    float inv = 1.f / fmaxf((float)(end - beg), 1.f);
    bf16x8 o;
    #pragma unroll
    for (int j = 0; j < 8; ++j) o[j] = (short)f2b(a[j]*inv);
    *(bf16x8*)(yb + (size_t)n*64 + f*8) = o;
  }
}

// ---------------- fused MLP via bf16 MFMA: 64-row tile, swapped-operand layout ----------------
// D^T trick: mfma(Wfrag, Afrag) -> each thread holds 4 CONSECUTIVE h-cols of ONE node.
// Same loads as the proven round-9 kernel; LN partial = local sum + 2 shfl_xor;
// h-write = ds_write_b64 x16; out = float4 x2.
__global__ __launch_bounds__(512, 4) void k_mlp(
    const ushort* __restrict__ cat0,              // xb; y1/y2/y3 at +PSTR each
    const ushort* __restrict__ W1t, const float* __restrict__ b1,
    const float* __restrict__ gamma, const float* __restrict__ beta,
    const ushort* __restrict__ W2t, const float* __restrict__ b2,
    float* __restrict__ out){
  constexpr size_t PSTR = 6400000;                // ushorts between concat parts
  __shared__ char lbuf[65536];                    // A tile 32KB; later h tile 64KB
  __shared__ float2 s_pair[8][64];
  __shared__ float2 s_stat2[64];

  int tid = threadIdx.x;
  int lane = tid & 63, wv = tid >> 6;
  int l15 = lane & 15, l4 = lane >> 4;

  int bid = blockIdx.x;
  {
    constexpr int NB = 1563, q = NB/8, r = NB%8;
    int xcd = bid & 7, idx = bid >> 3;
    bid = (xcd < r ? xcd*(q+1) : r*(q+1) + (xcd-r)*q) + idx;
  }
  int nbase = bid * 64;

  // ---- stage A (64x256 bf16, XOR-swizzled) via global_load_lds ----
  #pragma unroll
  for (int i = 0; i < 4; ++i){
    int dest = (wv*4 + i)*1024 + lane*16;
    int row = dest >> 9;
    int kbyte = (dest & 511) ^ ((row & 7) << 4);
    const ushort* src = cat0 + (size_t)(kbyte >> 7)*PSTR
                             + (size_t)(nbase + row)*64 + ((kbyte & 127) >> 1);
    __builtin_amdgcn_global_load_lds(
        (const __attribute__((address_space(1))) void*)src,
        (__attribute__((address_space(3))) void*)(lbuf + (wv*4 + i)*1024),
        16, 0, 0);
  }
  __syncthreads();                                 // (0)

  #define LOADA(kb, d)                                                          \
    { _Pragma("unroll")                                                         \
      for (int nt = 0; nt < 4; ++nt){                                           \
        int row_ = nt*16 + l15;                                                 \
        d[nt] = *(const bf16x8*)(lbuf + row_*512 +                              \
                 (((kb)*64 + l4*16) ^ ((row_ & 7) << 4)));                      \
      } }
  #define LOADB(kb, d)                                                          \
    { _Pragma("unroll")                                                         \
      for (int ct = 0; ct < 4; ++ct)                                            \
        d[ct] = *(const bf16x8*)(W1t + (size_t)(wv*64 + ct*16 + l15)*256 +      \
                                 (kb)*32 + l4*8); }

  // ---- GEMM1 swapped: acc[ct][nt] = D^T; thread = node (l15), cols l4*4+reg ----
  f32x4 acc[4][4] = {};
  {
    bf16x8 a[4], b[2][4];
    LOADB(0, b[0]);
    #pragma unroll
    for (int kb = 0; kb < 8; ++kb){
      int cur = kb & 1, nxt = cur ^ 1;
      if (kb < 7) LOADB(kb+1, b[nxt]);
      LOADA(kb, a);
      #pragma unroll
      for (int ct = 0; ct < 4; ++ct)
        #pragma unroll
        for (int nt = 0; nt < 4; ++nt)
          acc[ct][nt] = __builtin_amdgcn_mfma_f32_16x16x32_bf16(b[cur][ct], a[nt], acc[ct][nt], 0, 0, 0);
    }
  }

  // ---- bias (float4 per ct, transient) ----
  #pragma unroll
  for (int ct = 0; ct < 4; ++ct){
    const float4 b14 = *(const float4*)&b1[wv*64 + ct*16 + l4*4];
    #pragma unroll
    for (int nt = 0; nt < 4; ++nt){
      acc[ct][nt][0] += b14.x; acc[ct][nt][1] += b14.y;
      acc[ct][nt][2] += b14.z; acc[ct][nt][3] += b14.w;
    }
  }

  // ---- LN partial stats: local 16-col sum + 2 shfl_xor across l4 ----
  #pragma unroll
  for (int nt = 0; nt < 4; ++nt){
    float s = 0.f, q = 0.f;
    #pragma unroll
    for (int ct = 0; ct < 4; ++ct)
      #pragma unroll
      for (int r = 0; r < 4; ++r){
        float v = acc[ct][nt][r];
        s += v; q += v*v;
      }
    s += __shfl_xor(s, 16); s += __shfl_xor(s, 32);
    q += __shfl_xor(q, 16); q += __shfl_xor(q, 32);
    if (l4 == 0) s_pair[wv][nt*16 + l15] = make_float2(s, q);
  }
  __syncthreads();                                 // (1) A reads done

  if (tid < 64){
    float s = 0.f, q = 0.f;
    #pragma unroll
    for (int w = 0; w < 8; ++w){ float2 p = s_pair[w][tid]; s += p.x; q += p.y; }
    float mu = s * (1.f/512.f);
    float var = q * (1.f/512.f) - mu*mu;
    s_stat2[tid] = make_float2(mu, rsqrtf(var + 1e-5f));
  }
  __syncthreads();                                 // (2)

  // ---- LN + ReLU -> h tile: packed ds_write_b64 (4 consecutive cols) ----
  #pragma unroll
  for (int ct = 0; ct < 4; ++ct){
    int col0 = wv*64 + ct*16 + l4*4;
    const float4 g4 = *(const float4*)&gamma[col0];
    const float4 e4 = *(const float4*)&beta[col0];
    #pragma unroll
    for (int nt = 0; nt < 4; ++nt){
      int node = nt*16 + l15;
      float2 st = s_stat2[node];
      ushort4 hv;
      hv.x = f2b(fmaxf((acc[ct][nt][0] - st.x)*st.y*g4.x + e4.x, 0.f));
      hv.y = f2b(fmaxf((acc[ct][nt][1] - st.x)*st.y*g4.y + e4.y, 0.f));
      hv.z = f2b(fmaxf((acc[ct][nt][2] - st.x)*st.y*g4.z + e4.z, 0.f));
      hv.w = f2b(fmaxf((acc[ct][nt][3] - st.x)*st.y*g4.w + e4.w, 0.f));
      *(ushort4*)(lbuf + node*1024 + ((col0*2) ^ ((node & 7) << 4))) = hv;
    }
  }
  __syncthreads();                                 // (3)

  // ---- GEMM2 swapped: wave -> node-tile nt2 = wv>>1, out-col tile pair otb ----
  int nt2 = wv >> 1;
  int otb = (wv & 1) * 2;
  int hrow = nt2*16 + l15;
  f32x4 acc2[2] = {};
  const ushort* w2a = W2t + (size_t)((otb+0)*16 + l15)*512 + l4*8;
  const ushort* w2c = W2t + (size_t)((otb+1)*16 + l15)*512 + l4*8;
  {
    bf16x8 hf[2], w2f[2][2];
    w2f[0][0] = *(const bf16x8*)(w2a);
    w2f[0][1] = *(const bf16x8*)(w2c);
    hf[0] = *(const bf16x8*)(lbuf + hrow*1024 + ((l4*16) ^ ((hrow & 7) << 4)));
    #pragma unroll
    for (int kb = 0; kb < 16; ++kb){
      int cur = kb & 1, nxt = cur ^ 1;
      if (kb < 15){
        w2f[nxt][0] = *(const bf16x8*)(w2a + (kb+1)*32);
        w2f[nxt][1] = *(const bf16x8*)(w2c + (kb+1)*32);
        hf[nxt] = *(const bf16x8*)(lbuf + hrow*1024 +
                    (((kb+1)*64 + l4*16) ^ ((hrow & 7) << 4)));
      }
      acc2[0] = __builtin_amdgcn_mfma_f32_16x16x32_bf16(w2f[cur][0], hf[cur], acc2[0], 0, 0, 0);
      acc2[1] = __builtin_amdgcn_mfma_f32_16x16x32_bf16(w2f[cur][1], hf[cur], acc2[1], 0, 0, 0);
    }
  }

  int gnode = nbase + hrow;
  if (gnode < NN){
    #pragma unroll
    for (int t_ = 0; t_ < 2; ++t_){
      int col0 = (otb + t_)*16 + l4*4;
      const float4 b24 = *(const float4*)&b2[col0];
      float4 o4;
      o4.x = acc2[t_][0] + b24.x;
      o4.y = acc2[t_][1] + b24.y;
      o4.z = acc2[t_][2] + b24.z;
      o4.w = acc2[t_][3] + b24.w;
      *(float4*)&out[(size_t)gnode*64 + col0] = o4;
    }
  }
  #undef LOADA
  #undef LOADB
}

extern "C" void kernel_launch(void* const* d_in, const int* in_sizes, int n_in,
                              void* d_out, int out_size, void* d_ws, size_t ws_size,
                              hipStream_t stream){
  const float* x     = (const float*)d_in[0];
  const int*   eidx  = (const int*)d_in[1];
  const float* wprop = (const float*)d_in[2];
  const float* W1    = (const float*)d_in[3];
  const float* b1    = (const float*)d_in[4];
  const float* gamma = (const float*)d_in[5];
  const float* beta  = (const float*)d_in[6];
  const float* W2    = (const float*)d_in[7];
  const float* b2    = (const float*)d_in[8];
  float* out = (float*)d_out;
  const int* srcA = eidx;
  const int* dstA = eidx + NE;

  char* ws = (char*)d_ws;
  int*    rowptr = (int*)(ws);                  // 400,128 B -> pad 400,384
  ushort* W1t    = (ushort*)(ws +   400384);    // 256 KB -> 662,528
  ushort* W2t    = (ushort*)(ws +   662528);    // 64 KB  -> 728,064
  float*  V2     = (float*)(ws +    728064);    // 16 KB  -> 744,448
  float*  V3     = (float*)(ws +    744448);    // 16 KB  -> 760,832
  int*    bukcur = (int*)(ws +      760832);    // pad -> 761,856
  int*    bukptr = (int*)(ws +      761856);    // pad -> 762,880
  int*    csr    = (int*)(ws +      762880);    // 6.4 MB -> 7,162,880
  int*    ebuf   = (int*)(ws +     7162880);    // 8,028,160 B -> 15,191,040
  ushort* xb     = (ushort*)(ws + 15191040);    // 12.8 MB -> 27,991,040
  ushort* y1     = (ushort*)(ws + 27991040);    // 12.8 MB -> 40,791,040
  ushort* y2     = (ushort*)(ws + 40791040);    // 12.8 MB -> 53,591,040
  ushort* y3     = (ushort*)(ws + 53591040);    // 12.8 MB -> 66,391,040

  // ---- CSR build (hierarchical bucketed counting sort) ----
  hipMemsetAsync(bukcur, 0, NBUK*sizeof(int), stream);
  k_part1<<<256, 512, 0, stream>>>(srcA, dstA, bukcur, ebuf);
  k_bscan<<<1, 256, 0, stream>>>(bukcur, bukptr);
  k_bfinal<<<NBUK, 512, 0, stream>>>(ebuf, bukcur, bukptr, rowptr, csr);

  // ---- weight/input prep ----
  k_xb<<<6250, 256, 0, stream>>>(x, xb);
  k_vchain<<<1, 256, 0, stream>>>(wprop, V2, V3);
  k_ueff<<<512, 256, 0, stream>>>(W1, wprop, V2, V3, W1t);
  k_w2t<<<64, 512, 0, stream>>>(W2, W2t);

  // ---- 3 hops ----
  k_aggb<<<25000, 256, 0, stream>>>(xb, rowptr, csr, y1);
  k_aggb<<<25000, 256, 0, stream>>>(y1, rowptr, csr, y2);
  k_aggb<<<25000, 256, 0, stream>>>(y2, rowptr, csr, y3);

  // ---- fused MLP (64-row tiles, swapped-operand layout) ----
  k_mlp<<<1563, 512, 0, stream>>>(xb, W1t, b1, gamma, beta, W2t, b2, out);
}

// Round 12
// 271.212 us; speedup vs baseline: 1.2528x; 1.2423x over previous
//
#include <hip/hip_runtime.h>

constexpr int NN = 100000;
constexpr int NE = 1600000;
constexpr int NBUK = 196;            // 512-node buckets: 196*512 = 100352 >= NN
constexpr int ECAP = 10240;          // bucket capacity (E[cnt]=8192, sigma~90)
constexpr int CHUNK = 6250;          // edges per k_part1 block (256 blocks exact)
constexpr int NPT = 13;              // ceil(6250/512)

typedef __attribute__((ext_vector_type(8))) short bf16x8;
typedef __attribute__((ext_vector_type(4))) float f32x4;

__device__ inline ushort f2b(float f){
  uint u = __float_as_uint(f);
  uint r = (u + 0x7FFFu + ((u >> 16) & 1u)) >> 16;
  return (ushort)r;
}
__device__ inline float b2f(ushort u){
  uint v = ((uint)u) << 16;
  return __uint_as_float(v);
}

template<int CTRL>
__device__ inline float dpp_xadd(float v){
  int j = __builtin_amdgcn_update_dpp(0, __float_as_int(v), CTRL, 0xF, 0xF, true);
  return v + __int_as_float(j);
}
__device__ inline float red16(float v){
  v = dpp_xadd<0xB1>(v);
  v = dpp_xadd<0x4E>(v);
  v = dpp_xadd<0x141>(v);
  v = dpp_xadd<0x140>(v);
  return v;
}

// ---------------- CSR build, phase 1: block-local binning (+ xb convert tail) ----------------
__global__ __launch_bounds__(512) void k_part1(const int* __restrict__ srcA,
                                               const int* __restrict__ dstA,
                                               int* __restrict__ bukcur,
                                               int* __restrict__ ebuf,
                                               const float* __restrict__ x,
                                               ushort* __restrict__ xb){
  __shared__ int stage[CHUNK];
  __shared__ unsigned char bstage[CHUNK];
  __shared__ int hist[256];
  __shared__ int lofs[256];
  __shared__ int lcur[NBUK];
  __shared__ int basebuf[NBUK];
  int t = threadIdx.x;
  int cbase = blockIdx.x * CHUNK;

  if (t < 256) hist[t] = 0;
  if (t < NBUK) lcur[t] = 0;
  __syncthreads();

  int pk[NPT], bb[NPT];
  #pragma unroll
  for (int j = 0; j < NPT; ++j){
    int i = t + j*512;
    bb[j] = -1;
    if (i < CHUNK){
      int e = cbase + i;
      int d = dstA[e];
      bb[j] = d >> 9;
      pk[j] = (srcA[e] << 9) | (d & 511);
      atomicAdd(&hist[bb[j]], 1);
    }
  }
  __syncthreads();

  int v = (t < 256) ? hist[t] : 0;
  if (t < 256) lofs[t] = v;
  __syncthreads();
  #pragma unroll
  for (int off = 1; off < 256; off <<= 1){
    int tv = (t < 256 && t >= off) ? lofs[t-off] : 0;
    __syncthreads();
    if (t < 256) lofs[t] += tv;
    __syncthreads();
  }
  if (t < 256) lofs[t] -= v;
  if (t < NBUK) basebuf[t] = atomicAdd(&bukcur[t], v);
  __syncthreads();

  #pragma unroll
  for (int j = 0; j < NPT; ++j){
    if (bb[j] >= 0){
      int p = atomicAdd(&lcur[bb[j]], 1);
      int slot = lofs[bb[j]] + p;
      stage[slot] = pk[j];
      bstage[slot] = (unsigned char)bb[j];
    }
  }
  __syncthreads();

  for (int i = t; i < CHUNK; i += 512){
    int b = bstage[i];
    int j = i - lofs[b];
    int pos = basebuf[b] + j;
    if (pos < ECAP) ebuf[b*ECAP + pos] = stage[i];
  }

  // ---- tail: x -> bf16 (grid-stride over 1.6M float4), independent work ----
  for (int i = blockIdx.x*512 + t; i < NN*16; i += 256*512){
    float4 vv = ((const float4*)x)[i];
    ushort4 o;
    o.x = f2b(vv.x); o.y = f2b(vv.y); o.z = f2b(vv.z); o.w = f2b(vv.w);
    ((ushort4*)xb)[i] = o;
  }
}

// per bucket: LDS count -> scan -> rbeg/deg + compact csr into FIXED window b*ECAP
__global__ __launch_bounds__(512) void k_bfinal(const int* __restrict__ ebuf,
                                                const int* __restrict__ bukcur,
                                                int* __restrict__ rbeg,
                                                int* __restrict__ degA,
                                                int* __restrict__ csr){
  __shared__ int lcnt[512];
  __shared__ int lscan[512];
  __shared__ int lcur[512];
  int b = blockIdx.x, t = threadIdx.x;
  int cnt = bukcur[b]; if (cnt > ECAP) cnt = ECAP;
  int base = b*ECAP, gbase = b*ECAP;

  lcnt[t] = 0; lcur[t] = 0;
  __syncthreads();
  for (int i = t; i < cnt; i += 512) atomicAdd(&lcnt[ebuf[base+i] & 511], 1);
  __syncthreads();
  int v = lcnt[t];
  lscan[t] = v; __syncthreads();
  #pragma unroll
  for (int off = 1; off < 512; off <<= 1){
    int tv = (t >= off) ? lscan[t-off] : 0;
    __syncthreads();
    lscan[t] += tv;
    __syncthreads();
  }
  int excl = lscan[t] - v;
  lcnt[t] = excl;
  int node = b*512 + t;
  if (node < NN){ rbeg[node] = gbase + excl; degA[node] = v; }
  __syncthreads();
  for (int i = t; i < cnt; i += 512){
    int p = ebuf[base+i];
    int d = p & 511;
    int pos = atomicAdd(&lcur[d], 1);
    csr[gbase + lcnt[d] + pos] = p >> 9;
  }
}

// ---------------- effective-weight prep ----------------
__global__ void k_vchain(const float* __restrict__ Wp, float* __restrict__ V2,
                         float* __restrict__ V3){
  __shared__ float sA[4096], sB[4096], sC[4096];
  int t = threadIdx.x;
  for (int i = t; i < 4096; i += 256){ sA[i] = Wp[i]; sB[i] = Wp[4096+i]; }
  __syncthreads();
  for (int i = t; i < 4096; i += 256){
    int r = i >> 6, c = i & 63; float s = 0.f;
    #pragma unroll 8
    for (int j = 0; j < 64; ++j) s += sA[r*64+j]*sB[j*64+c];
    sC[i] = s; V2[i] = s;
  }
  __syncthreads();
  for (int i = t; i < 4096; i += 256) sB[i] = Wp[8192+i];
  __syncthreads();
  for (int i = t; i < 4096; i += 256){
    int r = i >> 6, c = i & 63; float s = 0.f;
    #pragma unroll 8
    for (int j = 0; j < 64; ++j) s += sC[r*64+j]*sB[j*64+c];
    V3[i] = s;
  }
}

__global__ void k_ueff(const float* __restrict__ W1, const float* __restrict__ Wp,
                       const float* __restrict__ V2, const float* __restrict__ V3,
                       ushort* __restrict__ W1t){
  __shared__ float col[256];
  int c = blockIdx.x, r = threadIdx.x;
  col[r] = W1[(size_t)r*512 + c];
  __syncthreads();
  int p = r >> 6, i = r & 63;
  float s;
  if (p == 0) s = col[r];
  else {
    const float* V = (p == 1) ? Wp : (p == 2) ? V2 : V3;
    s = 0.f;
    #pragma unroll 8
    for (int j = 0; j < 64; ++j) s += V[i*64+j]*col[p*64+j];
  }
  W1t[c*256 + r] = f2b(s);
}

__global__ void k_w2t(const float* __restrict__ W2, ushort* __restrict__ W2t){
  int col = blockIdx.x, k = threadIdx.x;
  W2t[col*512 + k] = f2b(W2[(size_t)k*64 + col]);
}

// ---------------- bf16 hop aggregation: 8 nodes/wave, lane = (feat-group, node) ----------------
// No cross-lane reduce; per-lane serial accumulation, 2-deep unroll; coalesced writes.
__global__ void k_aggb(const ushort* __restrict__ hb, const int* __restrict__ rbeg,
                       const int* __restrict__ degA, const int* __restrict__ csr,
                       ushort* __restrict__ yb){
  int lane = threadIdx.x & 63;
  int wv = threadIdx.x >> 6;
  int f = lane & 7, s = lane >> 3;
  int n = blockIdx.x*32 + wv*8 + s;              // 3125 blocks * 32 nodes = 100000 exact
  int beg = rbeg[n], dg = degA[n];
  float a[8] = {};
  int i = 0;
  for (; i + 2 <= dg; i += 2){
    int i0 = csr[beg+i], i1 = csr[beg+i+1];
    bf16x8 v0 = *(const bf16x8*)(hb + (size_t)i0*64 + f*8);
    bf16x8 v1 = *(const bf16x8*)(hb + (size_t)i1*64 + f*8);
    #pragma unroll
    for (int j = 0; j < 8; ++j)
      a[j] += b2f((ushort)v0[j]) + b2f((ushort)v1[j]);
  }
  if (i < dg){
    int i0 = csr[beg+i];
    bf16x8 v = *(const bf16x8*)(hb + (size_t)i0*64 + f*8);
    #pragma unroll
    for (int j = 0; j < 8; ++j) a[j] += b2f((ushort)v[j]);
  }
  float inv = 1.f / fmaxf((float)dg, 1.f);
  bf16x8 o;
  #pragma unroll
  for (int j = 0; j < 8; ++j) o[j] = (short)f2b(a[j]*inv);
  *(bf16x8*)(yb + (size_t)n*64 + f*8) = o;
}

// ---------------- fused MLP via bf16 MFMA (round-9 known-good structure) ----------------
__global__ __launch_bounds__(512, 4) void k_mlp(
    const ushort* __restrict__ cat0,              // xb; y1/y2/y3 at +PSTR each
    const ushort* __restrict__ W1t, const float* __restrict__ b1,
    const float* __restrict__ gamma, const float* __restrict__ beta,
    const ushort* __restrict__ W2t, const float* __restrict__ b2,
    float* __restrict__ out){
  constexpr size_t PSTR = 6400000;                // ushorts between concat parts
  __shared__ char lbuf[65536];
  __shared__ float2 s_pair[8][64];
  __shared__ float2 s_stat2[64];

  int tid = threadIdx.x;
  int lane = tid & 63, wv = tid >> 6;
  int l15 = lane & 15, l4 = lane >> 4;

  int bid = blockIdx.x;
  {
    constexpr int NB = 1563, q = NB/8, r = NB%8;
    int xcd = bid & 7, idx = bid >> 3;
    bid = (xcd < r ? xcd*(q+1) : r*(q+1) + (xcd-r)*q) + idx;
  }
  int nbase = bid * 64;

  #pragma unroll
  for (int i = 0; i < 4; ++i){
    int dest = (wv*4 + i)*1024 + lane*16;
    int row = dest >> 9;
    int kbyte = (dest & 511) ^ ((row & 7) << 4);
    const ushort* src = cat0 + (size_t)(kbyte >> 7)*PSTR
                             + (size_t)(nbase + row)*64 + ((kbyte & 127) >> 1);
    __builtin_amdgcn_global_load_lds(
        (const __attribute__((address_space(1))) void*)src,
        (__attribute__((address_space(3))) void*)(lbuf + (wv*4 + i)*1024),
        16, 0, 0);
  }
  __syncthreads();

  #define LOADA(kb, d)                                                          \
    { _Pragma("unroll")                                                         \
      for (int rt = 0; rt < 4; ++rt){                                           \
        int row_ = rt*16 + l15;                                                 \
        d[rt] = *(const bf16x8*)(lbuf + row_*512 +                              \
                 (((kb)*64 + l4*16) ^ ((row_ & 7) << 4)));                      \
      } }
  #define LOADB(kb, d)                                                          \
    { _Pragma("unroll")                                                         \
      for (int ci = 0; ci < 4; ++ci)                                            \
        d[ci] = *(const bf16x8*)(W1t + (size_t)(wv*64 + ci*16 + l15)*256 +      \
                                 (kb)*32 + l4*8); }

  f32x4 acc[4][4] = {};
  bf16x8 a[4], b[2][4];
  LOADB(0, b[0]);
  #pragma unroll
  for (int kb = 0; kb < 8; ++kb){
    int cur = kb & 1, nxt = cur ^ 1;
    if (kb < 7) LOADB(kb+1, b[nxt]);
    LOADA(kb, a);
    #pragma unroll
    for (int rt = 0; rt < 4; ++rt)
      #pragma unroll
      for (int ci = 0; ci < 4; ++ci)
        acc[rt][ci] = __builtin_amdgcn_mfma_f32_16x16x32_bf16(a[rt], b[cur][ci], acc[rt][ci], 0, 0, 0);
  }

  float bcol[4], gcol[4], ecol[4];
  #pragma unroll
  for (int ci = 0; ci < 4; ++ci){
    int col = wv*64 + ci*16 + l15;
    bcol[ci] = b1[col]; gcol[ci] = gamma[col]; ecol[ci] = beta[col];
  }
  #pragma unroll
  for (int rt = 0; rt < 4; ++rt)
    #pragma unroll
    for (int ci = 0; ci < 4; ++ci)
      #pragma unroll
      for (int r = 0; r < 4; ++r)
        acc[rt][ci][r] += bcol[ci];

  #pragma unroll
  for (int rt = 0; rt < 4; ++rt){
    #pragma unroll
    for (int r = 0; r < 4; ++r){
      float s = 0.f, q = 0.f;
      #pragma unroll
      for (int ci = 0; ci < 4; ++ci){
        float v = acc[rt][ci][r];
        s += v; q += v*v;
      }
      s = red16(s);
      q = red16(q);
      if (l15 == 0) s_pair[wv][rt*16 + l4*4 + r] = make_float2(s, q);
    }
  }
  __syncthreads();

  if (tid < 64){
    float s = 0.f, q = 0.f;
    #pragma unroll
    for (int w = 0; w < 8; ++w){ float2 p = s_pair[w][tid]; s += p.x; q += p.y; }
    float mu = s * (1.f/512.f);
    float var = q * (1.f/512.f) - mu*mu;
    s_stat2[tid] = make_float2(mu, rsqrtf(var + 1e-5f));
  }
  __syncthreads();

  #pragma unroll
  for (int rt = 0; rt < 4; ++rt){
    #pragma unroll
    for (int r = 0; r < 4; ++r){
      int row = rt*16 + l4*4 + r;
      float2 st = s_stat2[row];
      #pragma unroll
      for (int ci = 0; ci < 4; ++ci){
        float hv = fmaxf((acc[rt][ci][r] - st.x)*st.y*gcol[ci] + ecol[ci], 0.f);
        int col = wv*64 + ci*16 + l15;
        *((ushort*)(lbuf + row*1024 + ((col*2) ^ ((row & 7) << 4)))) = f2b(hv);
      }
    }
  }
  __syncthreads();

  #define LOADH(kb, d)                                                          \
    { _Pragma("unroll")                                                         \
      for (int t = 0; t < 2; ++t){                                              \
        int row_ = (rtb + t)*16 + l15;                                          \
        d[t] = *(const bf16x8*)(lbuf + row_*1024 +                              \
                 (((kb)*64 + l4*16) ^ ((row_ & 7) << 4)));                      \
      } }

  int ct = wv >> 1;
  int rtb = (wv & 1) * 2;
  f32x4 acc2[2] = {};
  const ushort* w2base = W2t + (size_t)(ct*16 + l15)*512 + l4*8;
  bf16x8 hb2[2][2], w2f[2];
  w2f[0] = *(const bf16x8*)(w2base);
  LOADH(0, hb2[0]);
  #pragma unroll
  for (int kb = 0; kb < 16; ++kb){
    int cur = kb & 1, nxt = cur ^ 1;
    if (kb < 15){
      w2f[nxt] = *(const bf16x8*)(w2base + (kb+1)*32);
      LOADH(kb+1, hb2[nxt]);
    }
    acc2[0] = __builtin_amdgcn_mfma_f32_16x16x32_bf16(hb2[cur][0], w2f[cur], acc2[0], 0, 0, 0);
    acc2[1] = __builtin_amdgcn_mfma_f32_16x16x32_bf16(hb2[cur][1], w2f[cur], acc2[1], 0, 0, 0);
  }

  float b2v = b2[ct*16 + l15];
  #pragma unroll
  for (int t = 0; t < 2; ++t){
    #pragma unroll
    for (int r = 0; r < 4; ++r){
      int row = (rtb + t)*16 + l4*4 + r;
      if (nbase + row < NN)
        out[(size_t)(nbase + row)*64 + ct*16 + l15] = acc2[t][r] + b2v;
    }
  }
  #undef LOADA
  #undef LOADB
  #undef LOADH
}

extern "C" void kernel_launch(void* const* d_in, const int* in_sizes, int n_in,
                              void* d_out, int out_size, void* d_ws, size_t ws_size,
                              hipStream_t stream){
  const float* x     = (const float*)d_in[0];
  const int*   eidx  = (const int*)d_in[1];
  const float* wprop = (const float*)d_in[2];
  const float* W1    = (const float*)d_in[3];
  const float* b1    = (const float*)d_in[4];
  const float* gamma = (const float*)d_in[5];
  const float* beta  = (const float*)d_in[6];
  const float* W2    = (const float*)d_in[7];
  const float* b2    = (const float*)d_in[8];
  float* out = (float*)d_out;
  const int* srcA = eidx;
  const int* dstA = eidx + NE;

  char* ws = (char*)d_ws;
  int*    rbeg   = (int*)(ws);                  //   400,000 -> pad   400,384
  int*    degA   = (int*)(ws +      400384);    //   400,000 -> pad   800,768
  ushort* W1t    = (ushort*)(ws +   800768);    //   262,144 ->     1,062,912
  ushort* W2t    = (ushort*)(ws +  1062912);    //    65,536 ->     1,128,448
  float*  V2     = (float*)(ws +   1128448);    //    16,384 ->     1,144,832
  float*  V3     = (float*)(ws +   1144832);    //    16,384 ->     1,161,216
  int*    bukcur = (int*)(ws +     1161216);    //       784 -> pad 1,162,240
  int*    csr    = (int*)(ws +     1162240);    // 8,028,160 ->     9,190,400
  int*    ebuf   = (int*)(ws +     9190400);    // 8,028,160 ->    17,218,560
  ushort* xb     = (ushort*)(ws + 17218560);    // 12.8 MB   ->    30,018,560
  ushort* y1     = (ushort*)(ws + 30018560);    // 12.8 MB   ->    42,818,560
  ushort* y2     = (ushort*)(ws + 42818560);    // 12.8 MB   ->    55,618,560
  ushort* y3     = (ushort*)(ws + 55618560);    // 12.8 MB   ->    68,418,560

  // ---- CSR build (fixed per-bucket windows; no global scan) ----
  hipMemsetAsync(bukcur, 0, NBUK*sizeof(int), stream);
  k_part1<<<256, 512, 0, stream>>>(srcA, dstA, bukcur, ebuf, x, xb);
  k_bfinal<<<NBUK, 512, 0, stream>>>(ebuf, bukcur, rbeg, degA, csr);

  // ---- weight prep ----
  k_vchain<<<1, 256, 0, stream>>>(wprop, V2, V3);
  k_ueff<<<512, 256, 0, stream>>>(W1, wprop, V2, V3, W1t);
  k_w2t<<<64, 512, 0, stream>>>(W2, W2t);

  // ---- 3 hops ----
  k_aggb<<<3125, 256, 0, stream>>>(xb, rbeg, degA, csr, y1);
  k_aggb<<<3125, 256, 0, stream>>>(y1, rbeg, degA, csr, y2);
  k_aggb<<<3125, 256, 0, stream>>>(y2, rbeg, degA, csr, y3);

  // ---- fused MLP ----
  k_mlp<<<1563, 512, 0, stream>>>(xb, W1t, b1, gamma, beta, W2t, b2, out);
}